// Round 15
// baseline (243.241 us; speedup 1.0000x reference)
//
#include <hip/hip_runtime.h>
#include <stdint.h>
#include <math.h>

#define DEV static __device__ __forceinline__

typedef __attribute__((ext_vector_type(8))) short bf16x8;
typedef __attribute__((ext_vector_type(4))) float f32x4;
typedef __attribute__((ext_vector_type(8))) unsigned short u16x8;
typedef __attribute__((ext_vector_type(4))) unsigned short u16x4;
typedef __attribute__((ext_vector_type(2))) unsigned int u32x2;

enum { B_ = 2, S_ = 2048, D_ = 2048, H_ = 32, HD_ = 64, N3_ = 6144, M_ = 4096 };

DEV unsigned short f2bf(float f) {
  unsigned u = __float_as_uint(f);
  u += 0x7FFFu + ((u >> 16) & 1u);
  return (unsigned short)(u >> 16);
}
DEV float bf2f(unsigned short s) { return __uint_as_float(((unsigned)s) << 16); }

DEV void load16(const void* g, void* l) {
  __builtin_amdgcn_global_load_lds((const __attribute__((address_space(1))) void*)g,
                                   (__attribute__((address_space(3))) void*)l,
                                   16, 0, 0);
}

DEV f32x4 mfma16(bf16x8 a, bf16x8 b, f32x4 c) {
  return __builtin_amdgcn_mfma_f32_16x16x32_bf16(a, b, c, 0, 0, 0);
}

// ------------------- fused prep: Wqkv^T | Wout^T | x->bf16 (one dispatch) -----
DEV void transpose_body(const float* __restrict__ W, unsigned short* __restrict__ Wt,
                        int Kg, int Ng, int tn, int tk, int t) {
  __shared__ float tile[32][33];
  const int r = t >> 3, c4 = (t & 7) * 4;
  float4 v = *(const float4*)(W + (size_t)(tk * 32 + r) * Ng + tn * 32 + c4);
  tile[r][c4 + 0] = v.x; tile[r][c4 + 1] = v.y;
  tile[r][c4 + 2] = v.z; tile[r][c4 + 3] = v.w;
  __syncthreads();
  u16x4 o;
  o[0] = f2bf(tile[c4 + 0][r]);
  o[1] = f2bf(tile[c4 + 1][r]);
  o[2] = f2bf(tile[c4 + 2][r]);
  o[3] = f2bf(tile[c4 + 3][r]);
  *(u16x4*)(Wt + (size_t)(tn * 32 + r) * Kg + tk * 32 + c4) = o;
}

__global__ __launch_bounds__(256) void prep_kernel(const float* __restrict__ x,
                                                   const float* __restrict__ Wqkv,
                                                   const float* __restrict__ Wout,
                                                   unsigned short* __restrict__ Xb,
                                                   unsigned short* __restrict__ Wqkvt,
                                                   unsigned short* __restrict__ Woutt) {
  const int bid = blockIdx.x, t = threadIdx.x;
  if (bid < 12288) {
    transpose_body(Wqkv, Wqkvt, 2048, 6144, bid % 192, bid / 192, t);
  } else if (bid < 16384) {
    const int r = bid - 12288;
    transpose_body(Wout, Woutt, 2048, 2048, r & 63, r >> 6, t);
  } else {
    const int i = (bid - 16384) * 256 + t;
    const float4* in4 = (const float4*)x;
    float4 a = in4[i * 2 + 0];
    float4 b = in4[i * 2 + 1];
    u16x8 o;
    o[0] = f2bf(a.x); o[1] = f2bf(a.y); o[2] = f2bf(a.z); o[3] = f2bf(a.w);
    o[4] = f2bf(b.x); o[5] = f2bf(b.y); o[6] = f2bf(b.z); o[7] = f2bf(b.w);
    *(u16x8*)(Xb + (size_t)i * 8) = o;
  }
}

// ============ 128x192 QKV GEMM, BK=64, 2-phase pipelined, 2 blocks/CU =========
// Race-safe vmcnt->barrier->read discipline (r11 fix). Validated r12: 115 us.
__global__ __launch_bounds__(256, 2) void gemm_qkv(const unsigned short* __restrict__ A,
                                                   const unsigned short* __restrict__ BT,
                                                   const float* __restrict__ bias,
                                                   unsigned short* __restrict__ Oqk,
                                                   unsigned short* __restrict__ vt,
                                                   int Mg, int Ng, int Kg) {
  __shared__ __align__(16) char lds[81920];
  const int tid = threadIdx.x;
  const int lane = tid & 63, w = tid >> 6;
  const int g = (lane >> 4) & 3, l16 = lane & 15;
  const int wn = w;

  const int wg = (blockIdx.x & 7) * (gridDim.x >> 3) + (blockIdx.x >> 3);
  const int nTM = Mg >> 7;
  const int tm = wg % nTM, tn = wg / nTM;
  const int rb = tm * 128, cb = tn * 192;
  const int NT = Kg >> 6;

  int c0, c1, c2;
  if (wn == 0)      { c0 = 0;   c1 = 16;  c2 = 32;  }
  else if (wn == 1) { c0 = 64;  c1 = 80;  c2 = 48;  }
  else if (wn == 2) { c0 = 128; c1 = 144; c2 = 96;  }
  else              { c0 = 112; c1 = 160; c2 = 176; }

  const int su0 = (g ^ (l16 & 7)) * 16;
  const int su1 = ((4 + g) ^ (l16 & 7)) * 16;
  const int offA = l16 * 128;
  const int offB0 = 16384 + (c0 + l16) * 128;
  const int offB1 = 16384 + (c1 + l16) * 128;
  const int offB2 = 16384 + (c2 + l16) * 128;

  const int r0 = tid >> 3;
  const int u8e = ((tid & 7) ^ (r0 & 7)) * 8;
  const unsigned short* sAa = A + (size_t)(rb + r0) * Kg + u8e;
  const unsigned short* sBb = BT + (size_t)(cb + r0) * Kg + u8e;
  const size_t rs32 = (size_t)Kg * 32;
  const int dstb = tid * 16;

  auto SA0 = [&](int t) { char* db = (char*)lds + ((t & 1) ? 40960 : 0);
    load16(sAa + (size_t)t * 64, db + dstb);
    load16(sAa + rs32 + (size_t)t * 64, db + 4096 + dstb); };
  auto SA1 = [&](int t) { char* db = (char*)lds + ((t & 1) ? 40960 : 0);
    load16(sAa + 2 * rs32 + (size_t)t * 64, db + 8192 + dstb);
    load16(sAa + 3 * rs32 + (size_t)t * 64, db + 12288 + dstb); };
  auto SB = [&](int t) { char* db = (char*)lds + ((t & 1) ? 40960 : 0) + 16384;
#pragma unroll
    for (int c = 0; c < 6; ++c)
      load16(sBb + c * rs32 + (size_t)t * 64, db + c * 4096 + dstb); };

  SA0(0); SA1(0); SB(0); SA0(1); SB(1);
  asm volatile("s_waitcnt vmcnt(8)" ::: "memory");
  __builtin_amdgcn_s_barrier();

  f32x4 acc[8][3] = {};
  bf16x8 a[4][2], b[3][2];

  for (int t = 0; t < NT; ++t) {
    const char* bs = (const char*)lds + ((t & 1) ? 40960 : 0);
#pragma unroll
    for (int mf = 0; mf < 4; ++mf) {
      a[mf][0] = *(const bf16x8*)(bs + offA + mf * 2048 + su0);
      a[mf][1] = *(const bf16x8*)(bs + offA + mf * 2048 + su1);
    }
    b[0][0] = *(const bf16x8*)(bs + offB0 + su0);
    b[0][1] = *(const bf16x8*)(bs + offB0 + su1);
    b[1][0] = *(const bf16x8*)(bs + offB1 + su0);
    b[1][1] = *(const bf16x8*)(bs + offB1 + su1);
    b[2][0] = *(const bf16x8*)(bs + offB2 + su0);
    b[2][1] = *(const bf16x8*)(bs + offB2 + su1);
    if (t + 1 < NT) SA1(t + 1);
    asm volatile("s_waitcnt lgkmcnt(8)" ::: "memory");
    __builtin_amdgcn_s_barrier();
    asm volatile("s_waitcnt lgkmcnt(0)" ::: "memory");
    __builtin_amdgcn_s_setprio(1);
#pragma unroll
    for (int mf = 0; mf < 4; ++mf)
#pragma unroll
      for (int nf = 0; nf < 3; ++nf)
#pragma unroll
        for (int kh = 0; kh < 2; ++kh)
          acc[mf][nf] = mfma16(a[mf][kh], b[nf][kh], acc[mf][nf]);
    __builtin_amdgcn_s_setprio(0);
    if (t == NT - 1) asm volatile("s_waitcnt vmcnt(0)" ::: "memory");
    else             asm volatile("s_waitcnt vmcnt(10)" ::: "memory");
    __builtin_amdgcn_s_barrier();
#pragma unroll
    for (int mf = 0; mf < 4; ++mf) {
      a[mf][0] = *(const bf16x8*)(bs + offA + (mf + 4) * 2048 + su0);
      a[mf][1] = *(const bf16x8*)(bs + offA + (mf + 4) * 2048 + su1);
    }
    if (t + 2 < NT) { SA0(t + 2); SB(t + 2); }
    __builtin_amdgcn_s_barrier();
    asm volatile("s_waitcnt lgkmcnt(0)" ::: "memory");
    __builtin_amdgcn_s_setprio(1);
#pragma unroll
    for (int mf = 0; mf < 4; ++mf)
#pragma unroll
      for (int nf = 0; nf < 3; ++nf)
#pragma unroll
        for (int kh = 0; kh < 2; ++kh)
          acc[mf + 4][nf] = mfma16(a[mf][kh], b[nf][kh], acc[mf + 4][nf]);
    __builtin_amdgcn_s_setprio(0);
    if (t + 2 < NT)      asm volatile("s_waitcnt vmcnt(10)" ::: "memory");
    else if (t + 1 < NT) asm volatile("s_waitcnt vmcnt(2)" ::: "memory");
    __builtin_amdgcn_s_barrier();
  }

  const int crow0 = rb + g * 4;
  const float bv0 = bias[cb + c0 + l16];
  const float bv1 = bias[cb + c1 + l16];
  const float bv2 = bias[cb + c2 + l16];
  const bool rotp = (wn < 3) && (cb + c0 < 4096);
  const float invf = exp2f(-(float)l16 * 0.83048202372184056f);  // 10000^(-l16/16)

#define STOREG(NF, CG, BV) do {                                                \
    const int col0_ = cb + (CG);                                               \
    if (col0_ >= 4096) {                                                       \
      const int hv_ = (col0_ - 4096) >> 6;                                     \
      const int dd_ = (col0_ & 63) + l16;                                      \
      _Pragma("unroll")                                                        \
      for (int mf = 0; mf < 8; ++mf) {                                         \
        int rowb_ = crow0 + mf * 16;                                           \
        int bb_ = rowb_ >> 11, s0_ = rowb_ & (S_ - 1);                         \
        u16x4 ov_;                                                             \
        _Pragma("unroll")                                                      \
        for (int r = 0; r < 4; ++r) ov_[r] = f2bf(acc[mf][NF][r] + (BV));      \
        *(u16x4*)(vt + ((size_t)(bb_ * 32 + hv_) * 64 + dd_) * S_ + s0_) = ov_;\
      }                                                                        \
    } else {                                                                   \
      _Pragma("unroll")                                                        \
      for (int mf = 0; mf < 8; ++mf)                                           \
        _Pragma("unroll")                                                      \
        for (int r = 0; r < 4; ++r) {                                          \
          int row_ = crow0 + mf * 16 + r;                                      \
          Oqk[(size_t)row_ * Ng + col0_ + l16] = f2bf(acc[mf][NF][r] + (BV));  \
        }                                                                      \
    }                                                                          \
  } while (0)

  if (rotp) {
#pragma unroll
    for (int mf = 0; mf < 8; ++mf)
#pragma unroll
      for (int r = 0; r < 4; ++r) {
        int row = crow0 + mf * 16 + r;
        float v0 = acc[mf][0][r] + bv0;
        float v1 = acc[mf][1][r] + bv1;
        float ang = (float)(row & (S_ - 1)) * invf;
        float sn = __sinf(ang), cs = __cosf(ang);
        float t0 = v0 * cs - v1 * sn;
        v1 = v0 * sn + v1 * cs;
        unsigned short* p = Oqk + (size_t)row * Ng;
        p[cb + c0 + l16] = f2bf(t0);
        p[cb + c1 + l16] = f2bf(v1);
      }
  } else {
    STOREG(0, c0, bv0);
    STOREG(1, c1, bv1);
  }
  STOREG(2, c2, bv2);
#undef STOREG
}

// ============ 128x128 OUT GEMM, BK=64, 2-phase pipelined, 2 blocks/CU =========
__global__ __launch_bounds__(256, 2) void gemm_out(const unsigned short* __restrict__ A,
                                                   const unsigned short* __restrict__ BT,
                                                   const float* __restrict__ bias,
                                                   float* __restrict__ Cout,
                                                   int Mg, int Ng, int Kg) {
  __shared__ __align__(16) char lds[65536];
  const int tid = threadIdx.x;
  const int lane = tid & 63, w = tid >> 6;
  const int g = (lane >> 4) & 3, l16 = lane & 15;
  const int wn = w;

  const int wg = (blockIdx.x & 7) * (gridDim.x >> 3) + (blockIdx.x >> 3);
  const int nTM = Mg >> 7;
  const int tm = wg % nTM, tn = wg / nTM;
  const int rb = tm * 128, cb = tn * 128;
  const int NT = Kg >> 6;

  const int su0 = (g ^ (l16 & 7)) * 16;
  const int su1 = ((4 + g) ^ (l16 & 7)) * 16;
  const int offA = l16 * 128;
  const int offB0 = 16384 + (wn * 32 + l16) * 128;
  const int offB1 = offB0 + 2048;  // +16 cols

  const int r0 = tid >> 3;
  const int u8e = ((tid & 7) ^ (r0 & 7)) * 8;
  const unsigned short* sAa = A + (size_t)(rb + r0) * Kg + u8e;
  const unsigned short* sBb = BT + (size_t)(cb + r0) * Kg + u8e;
  const size_t rs32 = (size_t)Kg * 32;
  const int dstb = tid * 16;

  auto SA0 = [&](int t) { char* db = (char*)lds + ((t & 1) ? 32768 : 0);
    load16(sAa + (size_t)t * 64, db + dstb);
    load16(sAa + rs32 + (size_t)t * 64, db + 4096 + dstb); };
  auto SA1 = [&](int t) { char* db = (char*)lds + ((t & 1) ? 32768 : 0);
    load16(sAa + 2 * rs32 + (size_t)t * 64, db + 8192 + dstb);
    load16(sAa + 3 * rs32 + (size_t)t * 64, db + 12288 + dstb); };
  auto SB = [&](int t) { char* db = (char*)lds + ((t & 1) ? 32768 : 0) + 16384;
#pragma unroll
    for (int c = 0; c < 4; ++c)
      load16(sBb + c * rs32 + (size_t)t * 64, db + c * 4096 + dstb); };

  SA0(0); SA1(0); SB(0); SA0(1); SB(1);
  asm volatile("s_waitcnt vmcnt(6)" ::: "memory");
  __builtin_amdgcn_s_barrier();

  f32x4 acc[8][2] = {};
  bf16x8 a[4][2], b[2][2];

  for (int t = 0; t < NT; ++t) {
    const char* bs = (const char*)lds + ((t & 1) ? 32768 : 0);
#pragma unroll
    for (int mf = 0; mf < 4; ++mf) {
      a[mf][0] = *(const bf16x8*)(bs + offA + mf * 2048 + su0);
      a[mf][1] = *(const bf16x8*)(bs + offA + mf * 2048 + su1);
    }
    b[0][0] = *(const bf16x8*)(bs + offB0 + su0);
    b[0][1] = *(const bf16x8*)(bs + offB0 + su1);
    b[1][0] = *(const bf16x8*)(bs + offB1 + su0);
    b[1][1] = *(const bf16x8*)(bs + offB1 + su1);
    if (t + 1 < NT) SA1(t + 1);
    asm volatile("s_waitcnt lgkmcnt(8)" ::: "memory");
    __builtin_amdgcn_s_barrier();
    asm volatile("s_waitcnt lgkmcnt(0)" ::: "memory");
    __builtin_amdgcn_s_setprio(1);
#pragma unroll
    for (int mf = 0; mf < 4; ++mf)
#pragma unroll
      for (int nf = 0; nf < 2; ++nf)
#pragma unroll
        for (int kh = 0; kh < 2; ++kh)
          acc[mf][nf] = mfma16(a[mf][kh], b[nf][kh], acc[mf][nf]);
    __builtin_amdgcn_s_setprio(0);
    if (t == NT - 1) asm volatile("s_waitcnt vmcnt(0)" ::: "memory");
    else             asm volatile("s_waitcnt vmcnt(8)" ::: "memory");
    __builtin_amdgcn_s_barrier();
#pragma unroll
    for (int mf = 0; mf < 4; ++mf) {
      a[mf][0] = *(const bf16x8*)(bs + offA + (mf + 4) * 2048 + su0);
      a[mf][1] = *(const bf16x8*)(bs + offA + (mf + 4) * 2048 + su1);
    }
    if (t + 2 < NT) { SA0(t + 2); SB(t + 2); }
    __builtin_amdgcn_s_barrier();
    asm volatile("s_waitcnt lgkmcnt(0)" ::: "memory");
    __builtin_amdgcn_s_setprio(1);
#pragma unroll
    for (int mf = 0; mf < 4; ++mf)
#pragma unroll
      for (int nf = 0; nf < 2; ++nf)
#pragma unroll
        for (int kh = 0; kh < 2; ++kh)
          acc[mf + 4][nf] = mfma16(a[mf][kh], b[nf][kh], acc[mf + 4][nf]);
    __builtin_amdgcn_s_setprio(0);
    if (t + 2 < NT)      asm volatile("s_waitcnt vmcnt(8)" ::: "memory");
    else if (t + 1 < NT) asm volatile("s_waitcnt vmcnt(2)" ::: "memory");
    __builtin_amdgcn_s_barrier();
  }

  const int crow0 = rb + g * 4;
  const int ccol0 = cb + wn * 32 + l16;
  const float bv0 = bias[ccol0];
  const float bv1 = bias[ccol0 + 16];
#pragma unroll
  for (int mf = 0; mf < 8; ++mf)
#pragma unroll
    for (int r = 0; r < 4; ++r) {
      int row = crow0 + mf * 16 + r;
      float* p = Cout + (size_t)row * Ng + ccol0;
      p[0] = acc[mf][0][r] + bv0;
      p[16] = acc[mf][1][r] + bv1;
    }
}

// ----------------------------------------------------------- flash attention
// 512 thr = 8 waves, 256 q-rows/block, grid 512 = 2 blocks/CU.
// launch_bounds(512,2): 256-VGPR cap -> no spill (r13's (512,4) forced 128-cap
// spill collapse). Tile-iterations per bh: 272 -> 144 (-47% staging/barriers).
// LDS 64KB: K dbuf 2x8K | V dbuf 2x8K | P 8 waves x 4K.
DEV void stage_kv(const unsigned short* __restrict__ qkv,
                  const unsigned short* __restrict__ vt,
                  unsigned char* lds, int bS, int bh64, int hoff, int kvb, int buf, int tid) {
  int row = tid >> 3, k8 = (tid & 7) ^ (row & 7);
  load16(qkv + (size_t)(bS + kvb + row) * N3_ + 2048 + hoff + 8 * k8,
         lds + buf * 8192 + tid * 16);
  load16(vt + (size_t)(bh64 + row) * S_ + kvb + 8 * k8,
         lds + 16384 + buf * 8192 + tid * 16);
}

__global__ __launch_bounds__(512, 2) void attn_kernel(const unsigned short* __restrict__ qkv,
                                                      const unsigned short* __restrict__ vt,
                                                      unsigned short* __restrict__ ao) {
  __shared__ __align__(16) unsigned char lds[65536];
  const int tid = threadIdx.x;
  const int lane = tid & 63, wv = tid >> 6;
  const int g = lane >> 4, l16 = lane & 15;
  const int bid = blockIdx.x;
  const int qi = 7 - (bid >> 6);  // LPT: big q-blocks first
  const int t6 = bid & 63;
  const int bh = ((t6 & 7) << 3) | (t6 >> 3);  // XCD grouping on bh
  const int b = bh >> 5, h = bh & 31;
  const int qbase = qi * 256;
  const int srow0 = qbase + wv * 32;
  const int bS = b * S_, bh64 = bh * 64, hoff = h * 64;

  bf16x8 qf[2][2];
#pragma unroll
  for (int m = 0; m < 2; ++m)
#pragma unroll
    for (int kt = 0; kt < 2; ++kt)
      qf[m][kt] = *(const bf16x8*)(qkv + (size_t)(bS + srow0 + m * 16 + l16) * N3_ +
                                   hoff + kt * 32 + g * 8);

  float mrun[2] = {-INFINITY, -INFINITY}, lrun[2] = {0.f, 0.f};
  f32x4 o[2][4] = {};
  unsigned char* pw = lds + 32768 + wv * 4096;

  const int nkv = (qbase + 256) >> 6;
  stage_kv(qkv, vt, lds, bS, bh64, hoff, 0, 0, tid);
  __syncthreads();

  for (int kb = 0; kb < nkv; ++kb) {
    const int cur = kb & 1;
    if (kb + 1 < nkv) stage_kv(qkv, vt, lds, bS, bh64, hoff, (kb + 1) << 6, cur ^ 1, tid);
    const int kvb = kb << 6;
    if (kvb <= srow0 + 31) {
      const unsigned char* kbuf = lds + cur * 8192;
      const unsigned char* vbuf = lds + 16384 + cur * 8192;

      f32x4 sc[2][4];
#pragma unroll
      for (int n = 0; n < 4; ++n) {
        int row = n * 16 + l16;
        bf16x8 kf0 = *(const bf16x8*)(kbuf + (row * 8 + ((g + 0) ^ (row & 7))) * 16);
        bf16x8 kf1 = *(const bf16x8*)(kbuf + (row * 8 + ((g + 4) ^ (row & 7))) * 16);
#pragma unroll
        for (int m = 0; m < 2; ++m) {
          f32x4 z = {};
          z = mfma16(kf0, qf[m][0], z);
          z = mfma16(kf1, qf[m][1], z);
          sc[m][n] = z;
        }
      }

      const bool boundary = (kvb + 63 > srow0);
#pragma unroll
      for (int m = 0; m < 2; ++m) {
        const int qrow = srow0 + m * 16 + l16;
        if (boundary) {
#pragma unroll
          for (int n = 0; n < 4; ++n)
#pragma unroll
            for (int r = 0; r < 4; ++r) {
              int k = kvb + n * 16 + g * 4 + r;
              if (k > qrow) sc[m][n][r] = -INFINITY;
            }
        }
        float mx = fmaxf(fmaxf(sc[m][0][0], sc[m][0][1]), fmaxf(sc[m][0][2], sc[m][0][3]));
#pragma unroll
        for (int n = 1; n < 4; ++n)
          mx = fmaxf(mx, fmaxf(fmaxf(sc[m][n][0], sc[m][n][1]), fmaxf(sc[m][n][2], sc[m][n][3])));
        mx = fmaxf(mx, __shfl_xor(mx, 16));
        mx = fmaxf(mx, __shfl_xor(mx, 32));
        float pm = mx * 0.125f;
        if (!__all(pm <= mrun[m] + 8.0f)) {
          float mn = fmaxf(mrun[m], pm);
          float al = exp2f((mrun[m] - mn) * 1.44269504f);
          mrun[m] = mn; lrun[m] *= al;
#pragma unroll
          for (int d = 0; d < 4; ++d) o[m][d] *= al;
        }
        const float mt = mrun[m] * 1.44269504f;
        float p[4][4]; float rs = 0.f;
#pragma unroll
        for (int n = 0; n < 4; ++n)
#pragma unroll
          for (int r = 0; r < 4; ++r) {
            p[n][r] = exp2f(fmaf(sc[m][n][r], 0.18033688011112042f, -mt));
            rs += p[n][r];
          }
        rs += __shfl_xor(rs, 16);
        rs += __shfl_xor(rs, 32);
        lrun[m] += rs;
#pragma unroll
        for (int n = 0; n < 4; ++n) {
          unsigned lo, hi;
          asm("v_cvt_pk_bf16_f32 %0, %1, %2" : "=v"(lo) : "v"(p[n][0]), "v"(p[n][1]));
          asm("v_cvt_pk_bf16_f32 %0, %1, %2" : "=v"(hi) : "v"(p[n][2]), "v"(p[n][3]));
          int su = (n * 4 + g) ^ ((l16 & 7) << 1);
          u32x2 wq; wq[0] = lo; wq[1] = hi;
          *(u32x2*)(pw + ((m * 16 + l16) * 16 + su) * 8) = wq;
        }
      }

      bf16x8 pf[2][2];
#pragma unroll
      for (int m = 0; m < 2; ++m)
#pragma unroll
        for (int kt = 0; kt < 2; ++kt) {
          int su = (kt * 8 + g * 2) ^ ((l16 & 7) << 1);
          pf[m][kt] = *(const bf16x8*)(pw + ((m * 16 + l16) * 16 + su) * 8);
        }
#pragma unroll
      for (int dblk = 0; dblk < 4; ++dblk) {
        int row = dblk * 16 + l16;
        bf16x8 vf0 = *(const bf16x8*)(vbuf + (row * 8 + ((g + 0) ^ (row & 7))) * 16);
        bf16x8 vf1 = *(const bf16x8*)(vbuf + (row * 8 + ((g + 4) ^ (row & 7))) * 16);
#pragma unroll
        for (int m = 0; m < 2; ++m) {
          o[m][dblk] = mfma16(vf0, pf[m][0], o[m][dblk]);
          o[m][dblk] = mfma16(vf1, pf[m][1], o[m][dblk]);
        }
      }
    }
    __syncthreads();
  }

#pragma unroll
  for (int m = 0; m < 2; ++m) {
    float inv = 1.0f / lrun[m];
    int q = srow0 + m * 16 + l16;
#pragma unroll
    for (int dblk = 0; dblk < 4; ++dblk) {
      u16x4 ov;
#pragma unroll
      for (int r = 0; r < 4; ++r) ov[r] = f2bf(o[m][dblk][r] * inv);
      *(u16x4*)(ao + (size_t)(bS + q) * D_ + hoff + dblk * 16 + g * 4) = ov;
    }
  }
}

// ---------------------------------------------------------------------- launch
extern "C" void kernel_launch(void* const* d_in, const int* in_sizes, int n_in,
                              void* d_out, int out_size, void* d_ws, size_t ws_size,
                              hipStream_t stream) {
  const float* x = (const float*)d_in[0];
  const float* Wqkv = (const float*)d_in[1];
  const float* bqkv = (const float*)d_in[2];
  const float* Wout = (const float*)d_in[3];
  const float* bout = (const float*)d_in[4];
  float* out = (float*)d_out;

  char* ws = (char*)d_ws;
  unsigned short* Xb = (unsigned short*)(ws + 0);                  // 16 MiB (reused as AO)
  unsigned short* Wqkvt = (unsigned short*)(ws + 16777216);        // 24 MiB
  unsigned short* Woutt = (unsigned short*)(ws + 41943040);        // 8 MiB
  unsigned short* QKVb = (unsigned short*)(ws + 50331648);         // 48 MiB
  unsigned short* Vt = (unsigned short*)(ws + 100663296);          // 16 MiB
  unsigned short* AO = Xb;  // Xb is dead after gemm1

  prep_kernel<<<20480, 256, 0, stream>>>(x, Wqkv, Wout, Xb, Wqkvt, Woutt);
  gemm_qkv<<<1024, 256, 0, stream>>>(Xb, Wqkvt, bqkv, QKVb, Vt, M_, N3_, D_);
  attn_kernel<<<512, 512, 0, stream>>>(QKVb, Vt, AO);
  gemm_out<<<512, 256, 0, stream>>>(AO, Woutt, bout, out, M_, D_, D_);
}

// Round 16
// 232.225 us; speedup vs baseline: 1.0474x; 1.0474x over previous
//
#include <hip/hip_runtime.h>
#include <stdint.h>
#include <math.h>

#define DEV static __device__ __forceinline__

typedef __attribute__((ext_vector_type(8))) short bf16x8;
typedef __attribute__((ext_vector_type(4))) float f32x4;
typedef __attribute__((ext_vector_type(8))) unsigned short u16x8;
typedef __attribute__((ext_vector_type(4))) unsigned short u16x4;
typedef __attribute__((ext_vector_type(2))) unsigned int u32x2;

enum { B_ = 2, S_ = 2048, D_ = 2048, H_ = 32, HD_ = 64, N3_ = 6144, M_ = 4096 };

DEV unsigned short f2bf(float f) {
  unsigned u = __float_as_uint(f);
  u += 0x7FFFu + ((u >> 16) & 1u);
  return (unsigned short)(u >> 16);
}
DEV float bf2f(unsigned short s) { return __uint_as_float(((unsigned)s) << 16); }

DEV void load16(const void* g, void* l) {
  __builtin_amdgcn_global_load_lds((const __attribute__((address_space(1))) void*)g,
                                   (__attribute__((address_space(3))) void*)l,
                                   16, 0, 0);
}

DEV f32x4 mfma16(bf16x8 a, bf16x8 b, f32x4 c) {
  return __builtin_amdgcn_mfma_f32_16x16x32_bf16(a, b, c, 0, 0, 0);
}

// ------------------- fused prep: Wqkv^T | Wout^T | x->bf16 (one dispatch) -----
DEV void transpose_body(const float* __restrict__ W, unsigned short* __restrict__ Wt,
                        int Kg, int Ng, int tn, int tk, int t) {
  __shared__ float tile[32][33];
  const int r = t >> 3, c4 = (t & 7) * 4;
  float4 v = *(const float4*)(W + (size_t)(tk * 32 + r) * Ng + tn * 32 + c4);
  tile[r][c4 + 0] = v.x; tile[r][c4 + 1] = v.y;
  tile[r][c4 + 2] = v.z; tile[r][c4 + 3] = v.w;
  __syncthreads();
  u16x4 o;
  o[0] = f2bf(tile[c4 + 0][r]);
  o[1] = f2bf(tile[c4 + 1][r]);
  o[2] = f2bf(tile[c4 + 2][r]);
  o[3] = f2bf(tile[c4 + 3][r]);
  *(u16x4*)(Wt + (size_t)(tn * 32 + r) * Kg + tk * 32 + c4) = o;
}

__global__ __launch_bounds__(256) void prep_kernel(const float* __restrict__ x,
                                                   const float* __restrict__ Wqkv,
                                                   const float* __restrict__ Wout,
                                                   unsigned short* __restrict__ Xb,
                                                   unsigned short* __restrict__ Wqkvt,
                                                   unsigned short* __restrict__ Woutt) {
  const int bid = blockIdx.x, t = threadIdx.x;
  if (bid < 12288) {
    transpose_body(Wqkv, Wqkvt, 2048, 6144, bid % 192, bid / 192, t);
  } else if (bid < 16384) {
    const int r = bid - 12288;
    transpose_body(Wout, Woutt, 2048, 2048, r & 63, r >> 6, t);
  } else {
    const int i = (bid - 16384) * 256 + t;
    const float4* in4 = (const float4*)x;
    float4 a = in4[i * 2 + 0];
    float4 b = in4[i * 2 + 1];
    u16x8 o;
    o[0] = f2bf(a.x); o[1] = f2bf(a.y); o[2] = f2bf(a.z); o[3] = f2bf(a.w);
    o[4] = f2bf(b.x); o[5] = f2bf(b.y); o[6] = f2bf(b.z); o[7] = f2bf(b.w);
    *(u16x8*)(Xb + (size_t)i * 8) = o;
  }
}

// ============ 128x192 QKV GEMM, BK=64, 2-phase pipelined, 2 blocks/CU =========
// Race-safe vmcnt->barrier->read discipline (r11 fix). Validated r12: 115 us.
__global__ __launch_bounds__(256, 2) void gemm_qkv(const unsigned short* __restrict__ A,
                                                   const unsigned short* __restrict__ BT,
                                                   const float* __restrict__ bias,
                                                   unsigned short* __restrict__ Oqk,
                                                   unsigned short* __restrict__ vt,
                                                   int Mg, int Ng, int Kg) {
  __shared__ __align__(16) char lds[81920];
  const int tid = threadIdx.x;
  const int lane = tid & 63, w = tid >> 6;
  const int g = (lane >> 4) & 3, l16 = lane & 15;
  const int wn = w;

  const int wg = (blockIdx.x & 7) * (gridDim.x >> 3) + (blockIdx.x >> 3);
  const int nTM = Mg >> 7;
  const int tm = wg % nTM, tn = wg / nTM;
  const int rb = tm * 128, cb = tn * 192;
  const int NT = Kg >> 6;

  int c0, c1, c2;
  if (wn == 0)      { c0 = 0;   c1 = 16;  c2 = 32;  }
  else if (wn == 1) { c0 = 64;  c1 = 80;  c2 = 48;  }
  else if (wn == 2) { c0 = 128; c1 = 144; c2 = 96;  }
  else              { c0 = 112; c1 = 160; c2 = 176; }

  const int su0 = (g ^ (l16 & 7)) * 16;
  const int su1 = ((4 + g) ^ (l16 & 7)) * 16;
  const int offA = l16 * 128;
  const int offB0 = 16384 + (c0 + l16) * 128;
  const int offB1 = 16384 + (c1 + l16) * 128;
  const int offB2 = 16384 + (c2 + l16) * 128;

  const int r0 = tid >> 3;
  const int u8e = ((tid & 7) ^ (r0 & 7)) * 8;
  const unsigned short* sAa = A + (size_t)(rb + r0) * Kg + u8e;
  const unsigned short* sBb = BT + (size_t)(cb + r0) * Kg + u8e;
  const size_t rs32 = (size_t)Kg * 32;
  const int dstb = tid * 16;

  auto SA0 = [&](int t) { char* db = (char*)lds + ((t & 1) ? 40960 : 0);
    load16(sAa + (size_t)t * 64, db + dstb);
    load16(sAa + rs32 + (size_t)t * 64, db + 4096 + dstb); };
  auto SA1 = [&](int t) { char* db = (char*)lds + ((t & 1) ? 40960 : 0);
    load16(sAa + 2 * rs32 + (size_t)t * 64, db + 8192 + dstb);
    load16(sAa + 3 * rs32 + (size_t)t * 64, db + 12288 + dstb); };
  auto SB = [&](int t) { char* db = (char*)lds + ((t & 1) ? 40960 : 0) + 16384;
#pragma unroll
    for (int c = 0; c < 6; ++c)
      load16(sBb + c * rs32 + (size_t)t * 64, db + c * 4096 + dstb); };

  SA0(0); SA1(0); SB(0); SA0(1); SB(1);
  asm volatile("s_waitcnt vmcnt(8)" ::: "memory");
  __builtin_amdgcn_s_barrier();

  f32x4 acc[8][3] = {};
  bf16x8 a[4][2], b[3][2];

  for (int t = 0; t < NT; ++t) {
    const char* bs = (const char*)lds + ((t & 1) ? 40960 : 0);
#pragma unroll
    for (int mf = 0; mf < 4; ++mf) {
      a[mf][0] = *(const bf16x8*)(bs + offA + mf * 2048 + su0);
      a[mf][1] = *(const bf16x8*)(bs + offA + mf * 2048 + su1);
    }
    b[0][0] = *(const bf16x8*)(bs + offB0 + su0);
    b[0][1] = *(const bf16x8*)(bs + offB0 + su1);
    b[1][0] = *(const bf16x8*)(bs + offB1 + su0);
    b[1][1] = *(const bf16x8*)(bs + offB1 + su1);
    b[2][0] = *(const bf16x8*)(bs + offB2 + su0);
    b[2][1] = *(const bf16x8*)(bs + offB2 + su1);
    if (t + 1 < NT) SA1(t + 1);
    asm volatile("s_waitcnt lgkmcnt(8)" ::: "memory");
    __builtin_amdgcn_s_barrier();
    asm volatile("s_waitcnt lgkmcnt(0)" ::: "memory");
    __builtin_amdgcn_s_setprio(1);
#pragma unroll
    for (int mf = 0; mf < 4; ++mf)
#pragma unroll
      for (int nf = 0; nf < 3; ++nf)
#pragma unroll
        for (int kh = 0; kh < 2; ++kh)
          acc[mf][nf] = mfma16(a[mf][kh], b[nf][kh], acc[mf][nf]);
    __builtin_amdgcn_s_setprio(0);
    if (t == NT - 1) asm volatile("s_waitcnt vmcnt(0)" ::: "memory");
    else             asm volatile("s_waitcnt vmcnt(10)" ::: "memory");
    __builtin_amdgcn_s_barrier();
#pragma unroll
    for (int mf = 0; mf < 4; ++mf) {
      a[mf][0] = *(const bf16x8*)(bs + offA + (mf + 4) * 2048 + su0);
      a[mf][1] = *(const bf16x8*)(bs + offA + (mf + 4) * 2048 + su1);
    }
    if (t + 2 < NT) { SA0(t + 2); SB(t + 2); }
    __builtin_amdgcn_s_barrier();
    asm volatile("s_waitcnt lgkmcnt(0)" ::: "memory");
    __builtin_amdgcn_s_setprio(1);
#pragma unroll
    for (int mf = 0; mf < 4; ++mf)
#pragma unroll
      for (int nf = 0; nf < 3; ++nf)
#pragma unroll
        for (int kh = 0; kh < 2; ++kh)
          acc[mf + 4][nf] = mfma16(a[mf][kh], b[nf][kh], acc[mf + 4][nf]);
    __builtin_amdgcn_s_setprio(0);
    if (t + 2 < NT)      asm volatile("s_waitcnt vmcnt(10)" ::: "memory");
    else if (t + 1 < NT) asm volatile("s_waitcnt vmcnt(2)" ::: "memory");
    __builtin_amdgcn_s_barrier();
  }

  const int crow0 = rb + g * 4;
  const float bv0 = bias[cb + c0 + l16];
  const float bv1 = bias[cb + c1 + l16];
  const float bv2 = bias[cb + c2 + l16];
  const bool rotp = (wn < 3) && (cb + c0 < 4096);
  const float invf = exp2f(-(float)l16 * 0.83048202372184056f);  // 10000^(-l16/16)

#define STOREG(NF, CG, BV) do {                                                \
    const int col0_ = cb + (CG);                                               \
    if (col0_ >= 4096) {                                                       \
      const int hv_ = (col0_ - 4096) >> 6;                                     \
      const int dd_ = (col0_ & 63) + l16;                                      \
      _Pragma("unroll")                                                        \
      for (int mf = 0; mf < 8; ++mf) {                                         \
        int rowb_ = crow0 + mf * 16;                                           \
        int bb_ = rowb_ >> 11, s0_ = rowb_ & (S_ - 1);                         \
        u16x4 ov_;                                                             \
        _Pragma("unroll")                                                      \
        for (int r = 0; r < 4; ++r) ov_[r] = f2bf(acc[mf][NF][r] + (BV));      \
        *(u16x4*)(vt + ((size_t)(bb_ * 32 + hv_) * 64 + dd_) * S_ + s0_) = ov_;\
      }                                                                        \
    } else {                                                                   \
      _Pragma("unroll")                                                        \
      for (int mf = 0; mf < 8; ++mf)                                           \
        _Pragma("unroll")                                                      \
        for (int r = 0; r < 4; ++r) {                                          \
          int row_ = crow0 + mf * 16 + r;                                      \
          Oqk[(size_t)row_ * Ng + col0_ + l16] = f2bf(acc[mf][NF][r] + (BV));  \
        }                                                                      \
    }                                                                          \
  } while (0)

  if (rotp) {
#pragma unroll
    for (int mf = 0; mf < 8; ++mf)
#pragma unroll
      for (int r = 0; r < 4; ++r) {
        int row = crow0 + mf * 16 + r;
        float v0 = acc[mf][0][r] + bv0;
        float v1 = acc[mf][1][r] + bv1;
        float ang = (float)(row & (S_ - 1)) * invf;
        float sn = __sinf(ang), cs = __cosf(ang);
        float t0 = v0 * cs - v1 * sn;
        v1 = v0 * sn + v1 * cs;
        unsigned short* p = Oqk + (size_t)row * Ng;
        p[cb + c0 + l16] = f2bf(t0);
        p[cb + c1 + l16] = f2bf(v1);
      }
  } else {
    STOREG(0, c0, bv0);
    STOREG(1, c1, bv1);
  }
  STOREG(2, c2, bv2);
#undef STOREG
}

// ============ 128x128 OUT GEMM, BK=64, 2-phase pipelined, 2 blocks/CU =========
__global__ __launch_bounds__(256, 2) void gemm_out(const unsigned short* __restrict__ A,
                                                   const unsigned short* __restrict__ BT,
                                                   const float* __restrict__ bias,
                                                   float* __restrict__ Cout,
                                                   int Mg, int Ng, int Kg) {
  __shared__ __align__(16) char lds[65536];
  const int tid = threadIdx.x;
  const int lane = tid & 63, w = tid >> 6;
  const int g = (lane >> 4) & 3, l16 = lane & 15;
  const int wn = w;

  const int wg = (blockIdx.x & 7) * (gridDim.x >> 3) + (blockIdx.x >> 3);
  const int nTM = Mg >> 7;
  const int tm = wg % nTM, tn = wg / nTM;
  const int rb = tm * 128, cb = tn * 128;
  const int NT = Kg >> 6;

  const int su0 = (g ^ (l16 & 7)) * 16;
  const int su1 = ((4 + g) ^ (l16 & 7)) * 16;
  const int offA = l16 * 128;
  const int offB0 = 16384 + (wn * 32 + l16) * 128;
  const int offB1 = offB0 + 2048;  // +16 cols

  const int r0 = tid >> 3;
  const int u8e = ((tid & 7) ^ (r0 & 7)) * 8;
  const unsigned short* sAa = A + (size_t)(rb + r0) * Kg + u8e;
  const unsigned short* sBb = BT + (size_t)(cb + r0) * Kg + u8e;
  const size_t rs32 = (size_t)Kg * 32;
  const int dstb = tid * 16;

  auto SA0 = [&](int t) { char* db = (char*)lds + ((t & 1) ? 32768 : 0);
    load16(sAa + (size_t)t * 64, db + dstb);
    load16(sAa + rs32 + (size_t)t * 64, db + 4096 + dstb); };
  auto SA1 = [&](int t) { char* db = (char*)lds + ((t & 1) ? 32768 : 0);
    load16(sAa + 2 * rs32 + (size_t)t * 64, db + 8192 + dstb);
    load16(sAa + 3 * rs32 + (size_t)t * 64, db + 12288 + dstb); };
  auto SB = [&](int t) { char* db = (char*)lds + ((t & 1) ? 32768 : 0) + 16384;
#pragma unroll
    for (int c = 0; c < 4; ++c)
      load16(sBb + c * rs32 + (size_t)t * 64, db + c * 4096 + dstb); };

  SA0(0); SA1(0); SB(0); SA0(1); SB(1);
  asm volatile("s_waitcnt vmcnt(6)" ::: "memory");
  __builtin_amdgcn_s_barrier();

  f32x4 acc[8][2] = {};
  bf16x8 a[4][2], b[2][2];

  for (int t = 0; t < NT; ++t) {
    const char* bs = (const char*)lds + ((t & 1) ? 32768 : 0);
#pragma unroll
    for (int mf = 0; mf < 4; ++mf) {
      a[mf][0] = *(const bf16x8*)(bs + offA + mf * 2048 + su0);
      a[mf][1] = *(const bf16x8*)(bs + offA + mf * 2048 + su1);
    }
    b[0][0] = *(const bf16x8*)(bs + offB0 + su0);
    b[0][1] = *(const bf16x8*)(bs + offB0 + su1);
    b[1][0] = *(const bf16x8*)(bs + offB1 + su0);
    b[1][1] = *(const bf16x8*)(bs + offB1 + su1);
    if (t + 1 < NT) SA1(t + 1);
    asm volatile("s_waitcnt lgkmcnt(8)" ::: "memory");
    __builtin_amdgcn_s_barrier();
    asm volatile("s_waitcnt lgkmcnt(0)" ::: "memory");
    __builtin_amdgcn_s_setprio(1);
#pragma unroll
    for (int mf = 0; mf < 4; ++mf)
#pragma unroll
      for (int nf = 0; nf < 2; ++nf)
#pragma unroll
        for (int kh = 0; kh < 2; ++kh)
          acc[mf][nf] = mfma16(a[mf][kh], b[nf][kh], acc[mf][nf]);
    __builtin_amdgcn_s_setprio(0);
    if (t == NT - 1) asm volatile("s_waitcnt vmcnt(0)" ::: "memory");
    else             asm volatile("s_waitcnt vmcnt(8)" ::: "memory");
    __builtin_amdgcn_s_barrier();
#pragma unroll
    for (int mf = 0; mf < 4; ++mf) {
      a[mf][0] = *(const bf16x8*)(bs + offA + (mf + 4) * 2048 + su0);
      a[mf][1] = *(const bf16x8*)(bs + offA + (mf + 4) * 2048 + su1);
    }
    if (t + 2 < NT) { SA0(t + 2); SB(t + 2); }
    __builtin_amdgcn_s_barrier();
    asm volatile("s_waitcnt lgkmcnt(0)" ::: "memory");
    __builtin_amdgcn_s_setprio(1);
#pragma unroll
    for (int mf = 0; mf < 4; ++mf)
#pragma unroll
      for (int nf = 0; nf < 2; ++nf)
#pragma unroll
        for (int kh = 0; kh < 2; ++kh)
          acc[mf + 4][nf] = mfma16(a[mf][kh], b[nf][kh], acc[mf + 4][nf]);
    __builtin_amdgcn_s_setprio(0);
    if (t + 2 < NT)      asm volatile("s_waitcnt vmcnt(8)" ::: "memory");
    else if (t + 1 < NT) asm volatile("s_waitcnt vmcnt(2)" ::: "memory");
    __builtin_amdgcn_s_barrier();
  }

  const int crow0 = rb + g * 4;
  const int ccol0 = cb + wn * 32 + l16;
  const float bv0 = bias[ccol0];
  const float bv1 = bias[ccol0 + 16];
#pragma unroll
  for (int mf = 0; mf < 8; ++mf)
#pragma unroll
    for (int r = 0; r < 4; ++r) {
      int row = crow0 + mf * 16 + r;
      float* p = Cout + (size_t)row * Ng + ccol0;
      p[0] = acc[mf][0][r] + bv0;
      p[16] = acc[mf][1][r] + bv1;
    }
}

// ----------------------------------------------------------- flash attention
// Round-12 validated version: 256 thr / 4 waves / 128 q-rows, 3 blocks/CU.
DEV void stage_kv(const unsigned short* __restrict__ qkv,
                  const unsigned short* __restrict__ vt,
                  unsigned char* lds, int bS, int bh64, int hoff, int kvb, int buf, int tid) {
#pragma unroll
  for (int c = 0; c < 2; ++c) {
    int p = c * 256 + tid;
    int row = p >> 3, k8 = (p & 7) ^ (row & 7);
    load16(qkv + (size_t)(bS + kvb + row) * N3_ + 2048 + hoff + 8 * k8,
           lds + buf * 8192 + p * 16);
    load16(vt + (size_t)(bh64 + row) * S_ + kvb + 8 * k8,
           lds + 16384 + buf * 8192 + p * 16);
  }
}

__global__ __launch_bounds__(256, 3) void attn_kernel(const unsigned short* __restrict__ qkv,
                                                      const unsigned short* __restrict__ vt,
                                                      unsigned short* __restrict__ ao) {
  __shared__ __align__(16) unsigned char lds[49152];
  const int tid = threadIdx.x;
  const int lane = tid & 63, wv = tid >> 6;
  const int g = lane >> 4, l16 = lane & 15;
  const int bid = blockIdx.x;
  const int qi = 15 - (bid >> 6);
  const int t6 = bid & 63;
  const int bh = ((t6 & 7) << 3) | (t6 >> 3);
  const int b = bh >> 5, h = bh & 31;
  const int qbase = qi * 128;
  const int srow0 = qbase + wv * 32;
  const int bS = b * S_, bh64 = bh * 64, hoff = h * 64;

  bf16x8 qf[2][2];
#pragma unroll
  for (int m = 0; m < 2; ++m)
#pragma unroll
    for (int kt = 0; kt < 2; ++kt)
      qf[m][kt] = *(const bf16x8*)(qkv + (size_t)(bS + srow0 + m * 16 + l16) * N3_ +
                                   hoff + kt * 32 + g * 8);

  float mrun[2] = {-INFINITY, -INFINITY}, lrun[2] = {0.f, 0.f};
  f32x4 o[2][4] = {};
  unsigned char* pw = lds + 32768 + wv * 4096;

  const int nkv = (qbase + 128) >> 6;
  stage_kv(qkv, vt, lds, bS, bh64, hoff, 0, 0, tid);
  __syncthreads();

  for (int kb = 0; kb < nkv; ++kb) {
    const int cur = kb & 1;
    if (kb + 1 < nkv) stage_kv(qkv, vt, lds, bS, bh64, hoff, (kb + 1) << 6, cur ^ 1, tid);
    const int kvb = kb << 6;
    if (kvb <= srow0 + 31) {
      const unsigned char* kbuf = lds + cur * 8192;
      const unsigned char* vbuf = lds + 16384 + cur * 8192;

      f32x4 sc[2][4];
#pragma unroll
      for (int n = 0; n < 4; ++n) {
        int row = n * 16 + l16;
        bf16x8 kf0 = *(const bf16x8*)(kbuf + (row * 8 + ((g + 0) ^ (row & 7))) * 16);
        bf16x8 kf1 = *(const bf16x8*)(kbuf + (row * 8 + ((g + 4) ^ (row & 7))) * 16);
#pragma unroll
        for (int m = 0; m < 2; ++m) {
          f32x4 z = {};
          z = mfma16(kf0, qf[m][0], z);
          z = mfma16(kf1, qf[m][1], z);
          sc[m][n] = z;
        }
      }

      const bool boundary = (kvb + 63 > srow0);
#pragma unroll
      for (int m = 0; m < 2; ++m) {
        const int qrow = srow0 + m * 16 + l16;
        if (boundary) {
#pragma unroll
          for (int n = 0; n < 4; ++n)
#pragma unroll
            for (int r = 0; r < 4; ++r) {
              int k = kvb + n * 16 + g * 4 + r;
              if (k > qrow) sc[m][n][r] = -INFINITY;
            }
        }
        float mx = fmaxf(fmaxf(sc[m][0][0], sc[m][0][1]), fmaxf(sc[m][0][2], sc[m][0][3]));
#pragma unroll
        for (int n = 1; n < 4; ++n)
          mx = fmaxf(mx, fmaxf(fmaxf(sc[m][n][0], sc[m][n][1]), fmaxf(sc[m][n][2], sc[m][n][3])));
        mx = fmaxf(mx, __shfl_xor(mx, 16));
        mx = fmaxf(mx, __shfl_xor(mx, 32));
        float pm = mx * 0.125f;
        if (!__all(pm <= mrun[m] + 8.0f)) {
          float mn = fmaxf(mrun[m], pm);
          float al = exp2f((mrun[m] - mn) * 1.44269504f);
          mrun[m] = mn; lrun[m] *= al;
#pragma unroll
          for (int d = 0; d < 4; ++d) o[m][d] *= al;
        }
        const float mt = mrun[m] * 1.44269504f;
        float p[4][4]; float rs = 0.f;
#pragma unroll
        for (int n = 0; n < 4; ++n)
#pragma unroll
          for (int r = 0; r < 4; ++r) {
            p[n][r] = exp2f(fmaf(sc[m][n][r], 0.18033688011112042f, -mt));
            rs += p[n][r];
          }
        rs += __shfl_xor(rs, 16);
        rs += __shfl_xor(rs, 32);
        lrun[m] += rs;
#pragma unroll
        for (int n = 0; n < 4; ++n) {
          unsigned lo, hi;
          asm("v_cvt_pk_bf16_f32 %0, %1, %2" : "=v"(lo) : "v"(p[n][0]), "v"(p[n][1]));
          asm("v_cvt_pk_bf16_f32 %0, %1, %2" : "=v"(hi) : "v"(p[n][2]), "v"(p[n][3]));
          int su = (n * 4 + g) ^ ((l16 & 7) << 1);
          u32x2 wq; wq[0] = lo; wq[1] = hi;
          *(u32x2*)(pw + ((m * 16 + l16) * 16 + su) * 8) = wq;
        }
      }

      bf16x8 pf[2][2];
#pragma unroll
      for (int m = 0; m < 2; ++m)
#pragma unroll
        for (int kt = 0; kt < 2; ++kt) {
          int su = (kt * 8 + g * 2) ^ ((l16 & 7) << 1);
          pf[m][kt] = *(const bf16x8*)(pw + ((m * 16 + l16) * 16 + su) * 8);
        }
#pragma unroll
      for (int dblk = 0; dblk < 4; ++dblk) {
        int row = dblk * 16 + l16;
        bf16x8 vf0 = *(const bf16x8*)(vbuf + (row * 8 + ((g + 0) ^ (row & 7))) * 16);
        bf16x8 vf1 = *(const bf16x8*)(vbuf + (row * 8 + ((g + 4) ^ (row & 7))) * 16);
#pragma unroll
        for (int m = 0; m < 2; ++m) {
          o[m][dblk] = mfma16(vf0, pf[m][0], o[m][dblk]);
          o[m][dblk] = mfma16(vf1, pf[m][1], o[m][dblk]);
        }
      }
    }
    __syncthreads();
  }

#pragma unroll
  for (int m = 0; m < 2; ++m) {
    float inv = 1.0f / lrun[m];
    int q = srow0 + m * 16 + l16;
#pragma unroll
    for (int dblk = 0; dblk < 4; ++dblk) {
      u16x4 ov;
#pragma unroll
      for (int r = 0; r < 4; ++r) ov[r] = f2bf(o[m][dblk][r] * inv);
      *(u16x4*)(ao + (size_t)(bS + q) * D_ + hoff + dblk * 16 + g * 4) = ov;
    }
  }
}

// ---------------------------------------------------------------------- launch
extern "C" void kernel_launch(void* const* d_in, const int* in_sizes, int n_in,
                              void* d_out, int out_size, void* d_ws, size_t ws_size,
                              hipStream_t stream) {
  const float* x = (const float*)d_in[0];
  const float* Wqkv = (const float*)d_in[1];
  const float* bqkv = (const float*)d_in[2];
  const float* Wout = (const float*)d_in[3];
  const float* bout = (const float*)d_in[4];
  float* out = (float*)d_out;

  char* ws = (char*)d_ws;
  unsigned short* Xb = (unsigned short*)(ws + 0);                  // 16 MiB (reused as AO)
  unsigned short* Wqkvt = (unsigned short*)(ws + 16777216);        // 24 MiB
  unsigned short* Woutt = (unsigned short*)(ws + 41943040);        // 8 MiB
  unsigned short* QKVb = (unsigned short*)(ws + 50331648);         // 48 MiB
  unsigned short* Vt = (unsigned short*)(ws + 100663296);          // 16 MiB
  unsigned short* AO = Xb;  // Xb is dead after gemm1

  prep_kernel<<<20480, 256, 0, stream>>>(x, Wqkv, Wout, Xb, Wqkvt, Woutt);
  gemm_qkv<<<1024, 256, 0, stream>>>(Xb, Wqkvt, bqkv, QKVb, Vt, M_, N3_, D_);
  attn_kernel<<<1024, 256, 0, stream>>>(QKVb, Vt, AO);
  gemm_out<<<512, 256, 0, stream>>>(AO, Woutt, bout, out, M_, D_, D_);
}